// Round 4
// baseline (281.810 us; speedup 1.0000x reference)
//
#include <hip/hip_runtime.h>
#include <hip/hip_bf16.h>
#include <stdint.h>

#define T_DIM 256
#define U_DIM 64
#define D_DIM 512
#define NIN 512
#define NV 4096

typedef __bf16 bf16x8 __attribute__((ext_vector_type(8)));
typedef float f32x4 __attribute__((ext_vector_type(4)));

static __device__ __forceinline__ unsigned short f2bf(float x) {
  union { float f; unsigned int u; } v; v.f = x;
  unsigned int r = v.u + 0x7FFFu + ((v.u >> 16) & 1u);
  return (unsigned short)(r >> 16);
}

static __device__ __forceinline__ void gload_lds16(const unsigned short* g, void* l) {
  __builtin_amdgcn_global_load_lds(
      (__attribute__((address_space(1))) void*)(unsigned short*)g,
      (__attribute__((address_space(3))) void*)l, 16, 0, 0);
}

// ---------------- W2 f32 -> bf16 ----------------
__global__ __launch_bounds__(256) void convert_w2_kernel(const float* __restrict__ W2,
                                                         unsigned short* __restrict__ W2b) {
  int q = blockIdx.x * 256 + threadIdx.x;
  const float4 v0 = *(const float4*)(W2 + (size_t)q * 8);
  const float4 v1 = *(const float4*)(W2 + (size_t)q * 8 + 4);
  union { unsigned short s[8]; uint4 u; } o;
  o.s[0] = f2bf(v0.x); o.s[1] = f2bf(v0.y); o.s[2] = f2bf(v0.z); o.s[3] = f2bf(v0.w);
  o.s[4] = f2bf(v1.x); o.s[5] = f2bf(v1.y); o.s[6] = f2bf(v1.z); o.s[7] = f2bf(v1.w);
  *(uint4*)(W2b + (size_t)q * 8) = o.u;
}

// ---------------- proj partials: {ep,dp}{0,1} = X @ W^T over K-half ----------------
__global__ __launch_bounds__(256) void proj_kernel(const float* __restrict__ enc,
                                                   const float* __restrict__ dec,
                                                   const float* __restrict__ W1,
                                                   float* __restrict__ ep0,
                                                   float* __restrict__ ep1,
                                                   float* __restrict__ dp0,
                                                   float* __restrict__ dp1) {
  __shared__ unsigned short As[128 * 32];
  __shared__ unsigned short Bs[128 * 32];
  const int tid = threadIdx.x;
  const int tile_m = blockIdx.x >> 3;
  const int kh = (blockIdx.x >> 2) & 1;
  const int tile_n = blockIdx.x & 3;
  const bool is_dec = (tile_m == 4);
  const float* X = is_dec ? dec : enc;
  const int xrow0 = is_dec ? 0 : tile_m * 128;
  const int wcol0 = is_dec ? D_DIM : 0;
  float* outp = is_dec ? (kh ? dp1 : dp0) : (kh ? ep1 : ep0);

  const int lane = tid & 63;
  const int wv = tid >> 6;
  const int wr = wv >> 1, wc = wv & 1;

  const int arow = tid >> 1;
  const int acol = (tid & 1) * 16;

  f32x4 acc[4][4] = {};

  const float* pa = X + (size_t)(xrow0 + arow) * D_DIM + acol;
  const float* pb = W1 + (size_t)(tile_n * 128 + arow) * (2 * D_DIM) + wcol0 + acol;

  for (int k0 = kh * 256; k0 < kh * 256 + 256; k0 += 32) {
    float4 av0 = *(const float4*)(pa + k0);
    float4 av1 = *(const float4*)(pa + k0 + 4);
    float4 av2 = *(const float4*)(pa + k0 + 8);
    float4 av3 = *(const float4*)(pa + k0 + 12);
    float4 bv0 = *(const float4*)(pb + k0);
    float4 bv1 = *(const float4*)(pb + k0 + 4);
    float4 bv2 = *(const float4*)(pb + k0 + 8);
    float4 bv3 = *(const float4*)(pb + k0 + 12);
    __syncthreads();
    union { unsigned short s[8]; uint4 u; } u0, u1, w0, w1;
    u0.s[0] = f2bf(av0.x); u0.s[1] = f2bf(av0.y); u0.s[2] = f2bf(av0.z); u0.s[3] = f2bf(av0.w);
    u0.s[4] = f2bf(av1.x); u0.s[5] = f2bf(av1.y); u0.s[6] = f2bf(av1.z); u0.s[7] = f2bf(av1.w);
    u1.s[0] = f2bf(av2.x); u1.s[1] = f2bf(av2.y); u1.s[2] = f2bf(av2.z); u1.s[3] = f2bf(av2.w);
    u1.s[4] = f2bf(av3.x); u1.s[5] = f2bf(av3.y); u1.s[6] = f2bf(av3.z); u1.s[7] = f2bf(av3.w);
    w0.s[0] = f2bf(bv0.x); w0.s[1] = f2bf(bv0.y); w0.s[2] = f2bf(bv0.z); w0.s[3] = f2bf(bv0.w);
    w0.s[4] = f2bf(bv1.x); w0.s[5] = f2bf(bv1.y); w0.s[6] = f2bf(bv1.z); w0.s[7] = f2bf(bv1.w);
    w1.s[0] = f2bf(bv2.x); w1.s[1] = f2bf(bv2.y); w1.s[2] = f2bf(bv2.z); w1.s[3] = f2bf(bv2.w);
    w1.s[4] = f2bf(bv3.x); w1.s[5] = f2bf(bv3.y); w1.s[6] = f2bf(bv3.z); w1.s[7] = f2bf(bv3.w);
    *(uint4*)&As[arow * 32 + acol] = u0.u;
    *(uint4*)&As[arow * 32 + acol + 8] = u1.u;
    *(uint4*)&Bs[arow * 32 + acol] = w0.u;
    *(uint4*)&Bs[arow * 32 + acol + 8] = w1.u;
    __syncthreads();
    bf16x8 af[4], bff[4];
#pragma unroll
    for (int mi = 0; mi < 4; ++mi)
      af[mi] = *(const bf16x8*)&As[(wr * 64 + mi * 16 + (lane & 15)) * 32 + (lane >> 4) * 8];
#pragma unroll
    for (int ni = 0; ni < 4; ++ni)
      bff[ni] = *(const bf16x8*)&Bs[(wc * 64 + ni * 16 + (lane & 15)) * 32 + (lane >> 4) * 8];
#pragma unroll
    for (int mi = 0; mi < 4; ++mi)
#pragma unroll
      for (int ni = 0; ni < 4; ++ni)
        acc[mi][ni] = __builtin_amdgcn_mfma_f32_16x16x32_bf16(af[mi], bff[ni], acc[mi][ni], 0, 0, 0);
  }

#pragma unroll
  for (int mi = 0; mi < 4; ++mi) {
#pragma unroll
    for (int r = 0; r < 4; ++r) {
      int row = xrow0 + wr * 64 + mi * 16 + ((lane >> 4) << 2) + r;
      float* po = outp + (size_t)row * NIN + tile_n * 128 + wc * 64 + (lane & 15);
#pragma unroll
      for (int ni = 0; ni < 4; ++ni) po[ni * 16] = acc[mi][ni][r];
    }
  }
}

// ---------------- H = tanh(ep0+ep1[bt] + dp0+dp1[bu] + b1) -> bf16 ----------------
__global__ __launch_bounds__(256) void h_kernel(const float* __restrict__ ep0,
                                                const float* __restrict__ ep1,
                                                const float* __restrict__ dp0,
                                                const float* __restrict__ dp1,
                                                const float* __restrict__ b1,
                                                unsigned short* __restrict__ Hb) {
  int q = blockIdx.x * 256 + threadIdx.x;
  int m = q >> 6;
  int i0 = (q & 63) << 3;
  size_t eoff = (size_t)(m >> 6) * NIN + i0;
  size_t doff = (size_t)((m >> 14) * U_DIM + (m & 63)) * NIN + i0;
  float4 e0 = *(const float4*)(ep0 + eoff);
  float4 e1 = *(const float4*)(ep0 + eoff + 4);
  float4 f0 = *(const float4*)(ep1 + eoff);
  float4 f1 = *(const float4*)(ep1 + eoff + 4);
  float4 d0 = *(const float4*)(dp0 + doff);
  float4 d1 = *(const float4*)(dp0 + doff + 4);
  float4 g0 = *(const float4*)(dp1 + doff);
  float4 g1 = *(const float4*)(dp1 + doff + 4);
  float4 c0 = *(const float4*)(b1 + i0);
  float4 c1 = *(const float4*)(b1 + i0 + 4);
  float x[8] = { e0.x + f0.x + d0.x + g0.x + c0.x, e0.y + f0.y + d0.y + g0.y + c0.y,
                 e0.z + f0.z + d0.z + g0.z + c0.z, e0.w + f0.w + d0.w + g0.w + c0.w,
                 e1.x + f1.x + d1.x + g1.x + c1.x, e1.y + f1.y + d1.y + g1.y + c1.y,
                 e1.z + f1.z + d1.z + g1.z + c1.z, e1.w + f1.w + d1.w + g1.w + c1.w };
  union { unsigned short s[8]; uint4 u; } o;
#pragma unroll
  for (int j = 0; j < 8; ++j) {
    float ex = __expf(2.0f * x[j]);
    float t = 1.0f - 2.0f / (ex + 1.0f);
    o.s[j] = f2bf(t);
  }
  *(uint4*)(Hb + (size_t)q * 8) = o.u;
}

// ---------------- persistent GEMM: out = H @ W2b^T + b2 ----------------
// 256 blocks (1/CU), each owns 128 M-rows, loops 16 n-tiles of 256 cols.
// Stream of 128 BK=64 tiles; 2 phases/tile; stores of n-tile j sprinkled
// into n-tile j+1 (4/phase); counted vmcnt incl. store tokens; 1 barrier/phase.
// LDS 96KB: A 2buf x 2kh x [128x32], B 2buf x 2kh x [256x32], seg-rot swizzle.
__global__ __launch_bounds__(512, 2) void gemm_persist_kernel(const unsigned short* __restrict__ Hb,
                                                              const unsigned short* __restrict__ W2b,
                                                              const float* __restrict__ b2,
                                                              float* __restrict__ outp) {
  __shared__ __align__(16) char smem[98304];
  const int tid = threadIdx.x;
  const int lane = tid & 63, w = tid >> 6;
  const int wr = w >> 2, wc = w & 3;
  const int m0 = blockIdx.x * 128;

  // staging source (pre-swizzled, round-3 proven)
  const int srow0 = (w << 4) + (lane >> 2);
  const int segp = ((((lane & 3) - ((lane >> 3) & 3)) & 3) << 3);
  const unsigned short* pA = Hb + (size_t)(m0 + srow0) * 512 + segp;
  const unsigned short* pB = W2b + (size_t)srow0 * 512 + segp;
  const int dstOff = (w << 10) | (lane << 4);
  const int laneA = ((lane & 15) << 6) | ((((lane >> 4) + ((lane >> 1) & 7)) & 3) << 4);

  f32x4 acc[4][4] = {};
  f32x4 old[4][4] = {};
  float b2v[4];
  bf16x8 af[4], bf[4];
  size_t scol = 0;

#define LDSA(b, k) (smem + (b) * 16384 + (k) * 8192)
#define LDSB(b, k) (smem + 32768 + (b) * 32768 + (k) * 16384)
#define BARR() __builtin_amdgcn_s_barrier()
#define WAITVM_(N) asm volatile("s_waitcnt vmcnt(" #N ")" ::: "memory")
#define WAITVM(N) WAITVM_(N)

#define RD8(b, k) do { \
    af[0] = *(const bf16x8*)(LDSA(b, k) + (wr << 12) + 0 + laneA); \
    af[1] = *(const bf16x8*)(LDSA(b, k) + (wr << 12) + 1024 + laneA); \
    af[2] = *(const bf16x8*)(LDSA(b, k) + (wr << 12) + 2048 + laneA); \
    af[3] = *(const bf16x8*)(LDSA(b, k) + (wr << 12) + 3072 + laneA); \
    bf[0] = *(const bf16x8*)(LDSB(b, k) + (wc << 12) + 0 + laneA); \
    bf[1] = *(const bf16x8*)(LDSB(b, k) + (wc << 12) + 1024 + laneA); \
    bf[2] = *(const bf16x8*)(LDSB(b, k) + (wc << 12) + 2048 + laneA); \
    bf[3] = *(const bf16x8*)(LDSB(b, k) + (wc << 12) + 3072 + laneA); \
  } while (0)

#define QUAD16() do { \
    __builtin_amdgcn_s_setprio(1); \
    _Pragma("unroll") for (int mi = 0; mi < 4; ++mi) \
      _Pragma("unroll") for (int ni = 0; ni < 4; ++ni) \
        acc[mi][ni] = __builtin_amdgcn_mfma_f32_16x16x32_bf16(af[mi], bf[ni], acc[mi][ni], 0, 0, 0); \
    __builtin_amdgcn_s_setprio(0); \
  } while (0)

#define STORE2(T, PH) do { \
    constexpr int F_ = 2 * (T) + (PH); \
    constexpr int MI_ = F_ >> 2, NI_ = F_ & 3; \
    float* po = outp + (size_t)(m0 + wr * 64 + MI_ * 16 + ((lane >> 4) << 2)) * NV \
                + scol + (wc << 6) + (NI_ << 4) + (lane & 15); \
    _Pragma("unroll") for (int r = 0; r < 4; ++r) po[(size_t)r * NV] = old[MI_][NI_][r]; \
  } while (0)

// tile T of current nt (buf = T&1); stages stream-tile T+1 into buf^1.
// W2N = vmcnt at end of PH0; W1N = vmcnt at end of PH1 (counted, incl stores).
#define TILE(T, S, W2N, W1N) do { \
    const int cb1 = (((T) + 1) & 7) << 6; \
    const int nboff1 = (nt + (((T) == 7) ? 1 : 0)) << 17; \
    /* PH0: stage t+1 A(kh0+kh1) + B(kh0); read kh0; 16 MFMA; stores; wait; bar */ \
    gload_lds16(pA + cb1,      LDSA(((T) + 1) & 1, 0) + dstOff); \
    gload_lds16(pA + cb1 + 32, LDSA(((T) + 1) & 1, 1) + dstOff); \
    gload_lds16(pB + nboff1 + cb1,         LDSB(((T) + 1) & 1, 0) + dstOff); \
    gload_lds16(pB + nboff1 + cb1 + 65536, LDSB(((T) + 1) & 1, 0) + 8192 + dstOff); \
    RD8((T) & 1, 0); \
    QUAD16(); \
    if (S) { STORE2(T, 0); } \
    WAITVM(W2N); BARR(); \
    /* PH1: stage t+1 B(kh1); read kh1; 16 MFMA; stores; wait; bar */ \
    gload_lds16(pB + nboff1 + cb1 + 32,         LDSB(((T) + 1) & 1, 1) + dstOff); \
    gload_lds16(pB + nboff1 + cb1 + 32 + 65536, LDSB(((T) + 1) & 1, 1) + 8192 + dstOff); \
    RD8((T) & 1, 1); \
    QUAD16(); \
    if (S) { STORE2(T, 1); } \
    WAITVM(W1N); BARR(); \
  } while (0)

#define B2LOAD(NT) do { \
    _Pragma("unroll") for (int ni = 0; ni < 4; ++ni) \
      b2v[ni] = b2[((NT) << 8) + (wc << 6) + (ni << 4) + (lane & 15)]; \
  } while (0)

#define BOUND() do { \
    _Pragma("unroll") for (int mi = 0; mi < 4; ++mi) \
      _Pragma("unroll") for (int ni = 0; ni < 4; ++ni) { \
        _Pragma("unroll") for (int r = 0; r < 4; ++r) old[mi][ni][r] = acc[mi][ni][r] + b2v[ni]; \
        acc[mi][ni] = (f32x4){0.f, 0.f, 0.f, 0.f}; \
      } \
  } while (0)

  // prologue: stage stream-tile 0 fully, drain, barrier
  gload_lds16(pA + 0,  LDSA(0, 0) + dstOff);
  gload_lds16(pA + 32, LDSA(0, 1) + dstOff);
  gload_lds16(pB + 0,          LDSB(0, 0) + dstOff);
  gload_lds16(pB + 65536,      LDSB(0, 0) + 8192 + dstOff);
  gload_lds16(pB + 32,         LDSB(0, 1) + dstOff);
  gload_lds16(pB + 32 + 65536, LDSB(0, 1) + 8192 + dstOff);
  WAITVM(0); BARR();

  {
    const int nt = 0;
    B2LOAD(0);
    TILE(0, 0, 4, 2); TILE(1, 0, 4, 2); TILE(2, 0, 4, 2); TILE(3, 0, 4, 2);
    TILE(4, 0, 4, 2); TILE(5, 0, 4, 2); TILE(6, 0, 4, 2); TILE(7, 0, 4, 2);
    BOUND();
  }
  {
    const int nt = 1;
    B2LOAD(1);
    scol = 0;
    TILE(0, 1, 8, 10);  // boundary: prev tile was store-less -> smaller count
    TILE(1, 1, 12, 10); TILE(2, 1, 12, 10); TILE(3, 1, 12, 10);
    TILE(4, 1, 12, 10); TILE(5, 1, 12, 10); TILE(6, 1, 12, 10); TILE(7, 1, 12, 10);
    BOUND();
  }
  for (int nt = 2; nt < 16; ++nt) {
    B2LOAD(nt);
    scol = (size_t)(nt - 1) << 8;
    TILE(0, 1, 12, 10); TILE(1, 1, 12, 10); TILE(2, 1, 12, 10); TILE(3, 1, 12, 10);
    TILE(4, 1, 12, 10); TILE(5, 1, 12, 10); TILE(6, 1, 12, 10); TILE(7, 1, 12, 10);
    BOUND();
  }

  // tail: store n-tile 15
  scol = (size_t)15 << 8;
#pragma unroll
  for (int mi = 0; mi < 4; ++mi) {
#pragma unroll
    for (int ni = 0; ni < 4; ++ni) {
      float* po = outp + (size_t)(m0 + wr * 64 + mi * 16 + ((lane >> 4) << 2)) * NV
                  + scol + (wc << 6) + (ni << 4) + (lane & 15);
#pragma unroll
      for (int r = 0; r < 4; ++r) po[(size_t)r * NV] = old[mi][ni][r];
    }
  }

#undef LDSA
#undef LDSB
#undef BARR
#undef WAITVM_
#undef WAITVM
#undef RD8
#undef QUAD16
#undef STORE2
#undef TILE
#undef B2LOAD
#undef BOUND
}

extern "C" void kernel_launch(void* const* d_in, const int* in_sizes, int n_in,
                              void* d_out, int out_size, void* d_ws, size_t ws_size,
                              hipStream_t stream) {
  const float* enc = (const float*)d_in[0];
  const float* dec = (const float*)d_in[1];
  const float* W1  = (const float*)d_in[2];
  const float* b1  = (const float*)d_in[3];
  const float* W2  = (const float*)d_in[4];
  const float* b2  = (const float*)d_in[5];
  float* out = (float*)d_out;

  char* ws = (char*)d_ws;
  unsigned short* W2b = (unsigned short*)(ws);                 // 4 MB
  float* ep0 = (float*)(ws + 4194304);                         // 1 MB
  float* ep1 = (float*)(ws + 5242880);                         // 1 MB
  float* dp0 = (float*)(ws + 6291456);                         // 256 KB
  float* dp1 = (float*)(ws + 6553600);                         // 256 KB
  unsigned short* Hb = (unsigned short*)(ws + 6815744);        // 32 MB

  hipLaunchKernelGGL(convert_w2_kernel, dim3(1024), dim3(256), 0, stream, W2, W2b);
  hipLaunchKernelGGL(proj_kernel, dim3(40), dim3(256), 0, stream, enc, dec, W1, ep0, ep1, dp0, dp1);
  hipLaunchKernelGGL(h_kernel, dim3(8192), dim3(256), 0, stream, ep0, ep1, dp0, dp1, b1, Hb);
  hipLaunchKernelGGL(gemm_persist_kernel, dim3(256), dim3(512), 0, stream, Hb, W2b, b2, out);
}

// Round 5
// 245.781 us; speedup vs baseline: 1.1466x; 1.1466x over previous
//
#include <hip/hip_runtime.h>
#include <hip/hip_bf16.h>
#include <stdint.h>

#define T_DIM 256
#define U_DIM 64
#define D_DIM 512
#define NIN 512
#define NV 4096

typedef __bf16 bf16x8 __attribute__((ext_vector_type(8)));
typedef float f32x4 __attribute__((ext_vector_type(4)));

static __device__ __forceinline__ unsigned short f2bf(float x) {
  union { float f; unsigned int u; } v; v.f = x;
  unsigned int r = v.u + 0x7FFFu + ((v.u >> 16) & 1u);
  return (unsigned short)(r >> 16);
}

static __device__ __forceinline__ void gload_lds16(const unsigned short* g, void* l) {
  __builtin_amdgcn_global_load_lds(
      (__attribute__((address_space(1))) void*)(unsigned short*)g,
      (__attribute__((address_space(3))) void*)l, 16, 0, 0);
}

// ---------------- fused prep: blocks 0..1023 convert W2; blocks 1024..1063 proj ----------------
__global__ __launch_bounds__(256) void prep_kernel(const float* __restrict__ W2,
                                                   unsigned short* __restrict__ W2b,
                                                   const float* __restrict__ enc,
                                                   const float* __restrict__ dec,
                                                   const float* __restrict__ W1,
                                                   float* __restrict__ ep0,
                                                   float* __restrict__ ep1,
                                                   float* __restrict__ dp0,
                                                   float* __restrict__ dp1) {
  __shared__ unsigned short As[128 * 32];
  __shared__ unsigned short Bs[128 * 32];
  const int tid = threadIdx.x;

  if (blockIdx.x < 1024) {
    int q = blockIdx.x * 256 + tid;
    const float4 v0 = *(const float4*)(W2 + (size_t)q * 8);
    const float4 v1 = *(const float4*)(W2 + (size_t)q * 8 + 4);
    union { unsigned short s[8]; uint4 u; } o;
    o.s[0] = f2bf(v0.x); o.s[1] = f2bf(v0.y); o.s[2] = f2bf(v0.z); o.s[3] = f2bf(v0.w);
    o.s[4] = f2bf(v1.x); o.s[5] = f2bf(v1.y); o.s[6] = f2bf(v1.z); o.s[7] = f2bf(v1.w);
    *(uint4*)(W2b + (size_t)q * 8) = o.u;
    return;
  }

  const int pbid = blockIdx.x - 1024;
  const int tile_m = pbid >> 3;
  const int kh = (pbid >> 2) & 1;
  const int tile_n = pbid & 3;
  const bool is_dec = (tile_m == 4);
  const float* X = is_dec ? dec : enc;
  const int xrow0 = is_dec ? 0 : tile_m * 128;
  const int wcol0 = is_dec ? D_DIM : 0;
  float* outp = is_dec ? (kh ? dp1 : dp0) : (kh ? ep1 : ep0);

  const int lane = tid & 63;
  const int wv = tid >> 6;
  const int wr = wv >> 1, wc = wv & 1;
  const int arow = tid >> 1;
  const int acol = (tid & 1) * 16;

  f32x4 acc[4][4] = {};

  const float* pa = X + (size_t)(xrow0 + arow) * D_DIM + acol;
  const float* pb = W1 + (size_t)(tile_n * 128 + arow) * (2 * D_DIM) + wcol0 + acol;

  for (int k0 = kh * 256; k0 < kh * 256 + 256; k0 += 32) {
    float4 av0 = *(const float4*)(pa + k0);
    float4 av1 = *(const float4*)(pa + k0 + 4);
    float4 av2 = *(const float4*)(pa + k0 + 8);
    float4 av3 = *(const float4*)(pa + k0 + 12);
    float4 bv0 = *(const float4*)(pb + k0);
    float4 bv1 = *(const float4*)(pb + k0 + 4);
    float4 bv2 = *(const float4*)(pb + k0 + 8);
    float4 bv3 = *(const float4*)(pb + k0 + 12);
    __syncthreads();
    union { unsigned short s[8]; uint4 u; } u0, u1, w0, w1;
    u0.s[0] = f2bf(av0.x); u0.s[1] = f2bf(av0.y); u0.s[2] = f2bf(av0.z); u0.s[3] = f2bf(av0.w);
    u0.s[4] = f2bf(av1.x); u0.s[5] = f2bf(av1.y); u0.s[6] = f2bf(av1.z); u0.s[7] = f2bf(av1.w);
    u1.s[0] = f2bf(av2.x); u1.s[1] = f2bf(av2.y); u1.s[2] = f2bf(av2.z); u1.s[3] = f2bf(av2.w);
    u1.s[4] = f2bf(av3.x); u1.s[5] = f2bf(av3.y); u1.s[6] = f2bf(av3.z); u1.s[7] = f2bf(av3.w);
    w0.s[0] = f2bf(bv0.x); w0.s[1] = f2bf(bv0.y); w0.s[2] = f2bf(bv0.z); w0.s[3] = f2bf(bv0.w);
    w0.s[4] = f2bf(bv1.x); w0.s[5] = f2bf(bv1.y); w0.s[6] = f2bf(bv1.z); w0.s[7] = f2bf(bv1.w);
    w1.s[0] = f2bf(bv2.x); w1.s[1] = f2bf(bv2.y); w1.s[2] = f2bf(bv2.z); w1.s[3] = f2bf(bv2.w);
    w1.s[4] = f2bf(bv3.x); w1.s[5] = f2bf(bv3.y); w1.s[6] = f2bf(bv3.z); w1.s[7] = f2bf(bv3.w);
    *(uint4*)&As[arow * 32 + acol] = u0.u;
    *(uint4*)&As[arow * 32 + acol + 8] = u1.u;
    *(uint4*)&Bs[arow * 32 + acol] = w0.u;
    *(uint4*)&Bs[arow * 32 + acol + 8] = w1.u;
    __syncthreads();
    bf16x8 af[4], bff[4];
#pragma unroll
    for (int mi = 0; mi < 4; ++mi)
      af[mi] = *(const bf16x8*)&As[(wr * 64 + mi * 16 + (lane & 15)) * 32 + (lane >> 4) * 8];
#pragma unroll
    for (int ni = 0; ni < 4; ++ni)
      bff[ni] = *(const bf16x8*)&Bs[(wc * 64 + ni * 16 + (lane & 15)) * 32 + (lane >> 4) * 8];
#pragma unroll
    for (int mi = 0; mi < 4; ++mi)
#pragma unroll
      for (int ni = 0; ni < 4; ++ni)
        acc[mi][ni] = __builtin_amdgcn_mfma_f32_16x16x32_bf16(af[mi], bff[ni], acc[mi][ni], 0, 0, 0);
  }

#pragma unroll
  for (int mi = 0; mi < 4; ++mi) {
#pragma unroll
    for (int r = 0; r < 4; ++r) {
      int row = xrow0 + wr * 64 + mi * 16 + ((lane >> 4) << 2) + r;
      float* po = outp + (size_t)row * NIN + tile_n * 128 + wc * 64 + (lane & 15);
#pragma unroll
      for (int ni = 0; ni < 4; ++ni) po[ni * 16] = acc[mi][ni][r];
    }
  }
}

// ---------------- H = tanh(ep0+ep1[bt] + dp0+dp1[bu] + b1) -> bf16 ----------------
__global__ __launch_bounds__(256) void h_kernel(const float* __restrict__ ep0,
                                                const float* __restrict__ ep1,
                                                const float* __restrict__ dp0,
                                                const float* __restrict__ dp1,
                                                const float* __restrict__ b1,
                                                unsigned short* __restrict__ Hb) {
  int q = blockIdx.x * 256 + threadIdx.x;
  int m = q >> 6;
  int i0 = (q & 63) << 3;
  size_t eoff = (size_t)(m >> 6) * NIN + i0;
  size_t doff = (size_t)((m >> 14) * U_DIM + (m & 63)) * NIN + i0;
  float4 e0 = *(const float4*)(ep0 + eoff);
  float4 e1 = *(const float4*)(ep0 + eoff + 4);
  float4 f0 = *(const float4*)(ep1 + eoff);
  float4 f1 = *(const float4*)(ep1 + eoff + 4);
  float4 d0 = *(const float4*)(dp0 + doff);
  float4 d1 = *(const float4*)(dp0 + doff + 4);
  float4 g0 = *(const float4*)(dp1 + doff);
  float4 g1 = *(const float4*)(dp1 + doff + 4);
  float4 c0 = *(const float4*)(b1 + i0);
  float4 c1 = *(const float4*)(b1 + i0 + 4);
  float x[8] = { e0.x + f0.x + d0.x + g0.x + c0.x, e0.y + f0.y + d0.y + g0.y + c0.y,
                 e0.z + f0.z + d0.z + g0.z + c0.z, e0.w + f0.w + d0.w + g0.w + c0.w,
                 e1.x + f1.x + d1.x + g1.x + c1.x, e1.y + f1.y + d1.y + g1.y + c1.y,
                 e1.z + f1.z + d1.z + g1.z + c1.z, e1.w + f1.w + d1.w + g1.w + c1.w };
  union { unsigned short s[8]; uint4 u; } o;
#pragma unroll
  for (int j = 0; j < 8; ++j) {
    float ex = __expf(2.0f * x[j]);
    float t = 1.0f - 2.0f / (ex + 1.0f);
    o.s[j] = f2bf(t);
  }
  *(uint4*)(Hb + (size_t)q * 8) = o.u;
}

// ---------------- main GEMM: out = H @ W2b^T + b2 ----------------
// 128x256 tile, BK=32, 8 waves (2x4), LDS 48KB -> 2 WGs/CU co-resident
// (launch_bounds(512,4) caps VGPR at 128). m97-style dbuf loop; one WG's
// vmcnt0 drain / epilogue store-stall overlaps the other WG's MFMA.
__global__ __launch_bounds__(512, 4) void gemm_kernel(const unsigned short* __restrict__ Hb,
                                                      const unsigned short* __restrict__ W2b,
                                                      const float* __restrict__ b2,
                                                      float* __restrict__ out) {
  __shared__ __align__(16) char smem[49152];  // A[2][8192] @0, B[2][16384] @16384
  const int tid = threadIdx.x;
  const int lane = tid & 63, w = tid >> 6;
  const int wr = w >> 2, wc = w & 3;
  const int bid = blockIdx.x;
  const int wg = ((bid & 7) << 9) | (bid >> 3);   // 4096 blocks, 512/XCD chunk
  const int tile_n = wg & 15, tile_m = wg >> 4;   // consecutive wg share tile_m (A-panel L2 reuse)
  const int m0 = tile_m * 128, n0 = tile_n * 256;

  // staging source (pre-swizzled seg-rot, R3-proven): lane l covers row 16w+(l>>2),
  // global seg ((l&3)-((l>>3)&3))&3; LDS dest linear w*1024 + l*16.
  const int srow = (w << 4) + (lane >> 2);
  const int segp = ((((lane & 3) - ((lane >> 3) & 3)) & 3) << 3);
  const unsigned short* pA = Hb + (size_t)(m0 + srow) * 512 + segp;
  const unsigned short* pB0 = W2b + (size_t)(n0 + srow) * 512 + segp;
  const unsigned short* pB1 = pB0 + 128 * 512;
  const int dstOff = (w << 10) | (lane << 4);
  // swizzled read: row r'=lane&15 within 1KB chunk, slot = (q + (r'>>1))&3, q=lane>>4
  const int laneA = ((lane & 15) << 6) | ((((lane >> 4) + ((lane >> 1) & 7)) & 3) << 4);

  f32x4 acc[4][4] = {};
  bf16x8 af[4], bf_[4];

  // prologue: stage k=0 into buf0
  gload_lds16(pA, smem + dstOff);
  gload_lds16(pB0, smem + 16384 + dstOff);
  gload_lds16(pB1, smem + 16384 + 8192 + dstOff);
  __syncthreads();  // compiler emits vmcnt(0) drain before barrier

#pragma unroll
  for (int k = 0; k < 16; ++k) {
    const int cur = k & 1;
    const int nxt = cur ^ 1;
    if (k < 15) {
      gload_lds16(pA + (k + 1) * 32, smem + nxt * 8192 + dstOff);
      gload_lds16(pB0 + (k + 1) * 32, smem + 16384 + nxt * 16384 + dstOff);
      gload_lds16(pB1 + (k + 1) * 32, smem + 16384 + nxt * 16384 + 8192 + dstOff);
    }
#pragma unroll
    for (int mi = 0; mi < 4; ++mi)
      af[mi] = *(const bf16x8*)(smem + cur * 8192 + ((wr * 4 + mi) << 10) + laneA);
#pragma unroll
    for (int ni = 0; ni < 4; ++ni)
      bf_[ni] = *(const bf16x8*)(smem + 16384 + cur * 16384 + ((wc * 4 + ni) << 10) + laneA);
    __builtin_amdgcn_s_setprio(1);
#pragma unroll
    for (int mi = 0; mi < 4; ++mi)
#pragma unroll
      for (int ni = 0; ni < 4; ++ni)
        acc[mi][ni] = __builtin_amdgcn_mfma_f32_16x16x32_bf16(af[mi], bf_[ni], acc[mi][ni], 0, 0, 0);
    __builtin_amdgcn_s_setprio(0);
    __syncthreads();
  }

  // epilogue: C = acc + b2 (R1-proven mapping)
  float b2v[4];
#pragma unroll
  for (int ni = 0; ni < 4; ++ni) b2v[ni] = b2[n0 + wc * 64 + ni * 16 + (lane & 15)];
#pragma unroll
  for (int mi = 0; mi < 4; ++mi) {
#pragma unroll
    for (int r = 0; r < 4; ++r) {
      int row = m0 + wr * 64 + mi * 16 + ((lane >> 4) << 2) + r;
      float* po = out + (size_t)row * NV + n0 + wc * 64 + (lane & 15);
#pragma unroll
      for (int ni = 0; ni < 4; ++ni) po[ni * 16] = acc[mi][ni][r] + b2v[ni];
    }
  }
}

extern "C" void kernel_launch(void* const* d_in, const int* in_sizes, int n_in,
                              void* d_out, int out_size, void* d_ws, size_t ws_size,
                              hipStream_t stream) {
  const float* enc = (const float*)d_in[0];
  const float* dec = (const float*)d_in[1];
  const float* W1  = (const float*)d_in[2];
  const float* b1  = (const float*)d_in[3];
  const float* W2  = (const float*)d_in[4];
  const float* b2  = (const float*)d_in[5];
  float* out = (float*)d_out;

  char* ws = (char*)d_ws;
  unsigned short* W2b = (unsigned short*)(ws);                 // 4 MB
  float* ep0 = (float*)(ws + 4194304);                         // 1 MB
  float* ep1 = (float*)(ws + 5242880);                         // 1 MB
  float* dp0 = (float*)(ws + 6291456);                         // 256 KB
  float* dp1 = (float*)(ws + 6553600);                         // 256 KB
  unsigned short* Hb = (unsigned short*)(ws + 6815744);        // 32 MB

  hipLaunchKernelGGL(prep_kernel, dim3(1064), dim3(256), 0, stream,
                     W2, W2b, enc, dec, W1, ep0, ep1, dp0, dp1);
  hipLaunchKernelGGL(h_kernel, dim3(8192), dim3(256), 0, stream, ep0, ep1, dp0, dp1, b1, Hb);
  hipLaunchKernelGGL(gemm_kernel, dim3(4096), dim3(512), 0, stream, Hb, W2b, b2, out);
}